// Round 7
// baseline (396.225 us; speedup 1.0000x reference)
//
#include <hip/hip_runtime.h>

// ProteinGCN: 2x GCNConv(+relu) + FC head. N=100k, E=1.6M, 64->128->64->1.
// Round 6: k_gemm12 was occupancy-bound (51.2 KB LDS -> 2 blocks/CU, 23% occ,
// 72 us vs 21 us FMA floor). Rewritten wave-local with ZERO LDS: one wave owns
// 16 nodes; agg tile distributed across lane registers, a[row][k] and
// h1[row][k] broadcast via __shfl (ds_bpermute, same-lane broadcast = no
// conflicts); h1 never leaves registers. No barriers at all.

constexpr int NN = 100000;
constexpr int NE = 1600000;
constexpr int D0 = 64;   // input dim
constexpr int D1 = 128;  // hidden 1
constexpr int D2 = 64;   // hidden 2
constexpr int NB = (NN + 255) / 256;  // 391 buckets
constexpr int TILE = 8192;            // edges per k_part block

// ---------------- CSR build ----------------

__global__ __launch_bounds__(256) void k_zero_cnt(int* __restrict__ cnt) {
    int i = blockIdx.x * 256 + threadIdx.x;
    if (i < NN) cnt[i] = 0;
}

__global__ __launch_bounds__(256) void k_hist(const int* __restrict__ dst,
                                              int* __restrict__ cnt) {
    int e = blockIdx.x * 256 + threadIdx.x;
    if (e < NE) atomicAdd(&cnt[dst[e]], 1);
}

__global__ __launch_bounds__(256) void k_scan_block(const int* __restrict__ cnt,
                                                    int* __restrict__ rowptr,
                                                    int* __restrict__ bsum) {
    __shared__ int s[256];
    int tid = threadIdx.x;
    int i = blockIdx.x * 256 + tid;
    int v = (i < NN) ? cnt[i] : 0;
    s[tid] = v;
    __syncthreads();
#pragma unroll
    for (int off = 1; off < 256; off <<= 1) {
        int t = (tid >= off) ? s[tid - off] : 0;
        __syncthreads();
        s[tid] += t;
        __syncthreads();
    }
    if (i < NN) rowptr[i] = s[tid] - v;  // exclusive
    if (tid == 255) bsum[blockIdx.x] = s[255];
}

__global__ __launch_bounds__(512) void k_scan_bsum(int* __restrict__ bsum,
                                                   int* __restrict__ gcur) {
    __shared__ int s[512];
    int tid = threadIdx.x;
    int v = (tid < NB) ? bsum[tid] : 0;
    s[tid] = v;
    __syncthreads();
#pragma unroll
    for (int off = 1; off < 512; off <<= 1) {
        int t = (tid >= off) ? s[tid - off] : 0;
        __syncthreads();
        s[tid] += t;
        __syncthreads();
    }
    int ex = s[tid] - v;  // exclusive scan
    if (tid <= NB) bsum[tid] = ex;   // bsum[NB] == NE
    if (tid < NB) gcur[tid] = ex;
}

__global__ __launch_bounds__(256) void k_scan_add(int* __restrict__ rowptr,
                                                  const int* __restrict__ bsum) {
    int i = blockIdx.x * 256 + threadIdx.x;
    if (i < NN) rowptr[i] += bsum[i >> 8];
    if (i == 0) rowptr[NN] = NE;
}

__global__ __launch_bounds__(256) void k_dinv(const int* __restrict__ cnt,
                                              float* __restrict__ dinv) {
    int i = blockIdx.x * 256 + threadIdx.x;
    if (i < NN) dinv[i] = rsqrtf((float)(cnt[i] + 1));
}

// ---- phase 1: partition edges into dst-buckets, packed (dl<<24)|src ----
__global__ __launch_bounds__(256) void k_part(const int* __restrict__ src,
                                              const int* __restrict__ dst,
                                              int* __restrict__ gcur,
                                              unsigned* __restrict__ packed) {
    __shared__ int cnt_s[NB];
    __shared__ int gbase_s[NB];
    __shared__ int cur_s[NB];
    int tid = threadIdx.x;
    int e0 = blockIdx.x * TILE;
    int ecnt = NE - e0 < TILE ? NE - e0 : TILE;
    for (int i = tid; i < NB; i += 256) cnt_s[i] = 0;
    __syncthreads();
    for (int i = tid; i < ecnt; i += 256)
        atomicAdd(&cnt_s[dst[e0 + i] >> 8], 1);
    __syncthreads();
    for (int i = tid; i < NB; i += 256) {
        int c = cnt_s[i];
        gbase_s[i] = c ? atomicAdd(&gcur[i], c) : 0;
        cur_s[i] = 0;
    }
    __syncthreads();
    for (int i = tid; i < ecnt; i += 256) {
        int d = dst[e0 + i];
        int s = src[e0 + i];
        int b = d >> 8;
        int slot = atomicAdd(&cur_s[b], 1);
        packed[gbase_s[b] + slot] = ((unsigned)(d & 255) << 24) | (unsigned)s;
    }
}

// ---- phase 2: one block per bucket, LDS node cursors, local col writes ----
__global__ __launch_bounds__(256) void k_fill2(const int* __restrict__ bsum,
                                               const int* __restrict__ rowptr,
                                               const unsigned* __restrict__ packed,
                                               int* __restrict__ col) {
    __shared__ int cur[256];
    int b = blockIdx.x;
    int n = (b << 8) + threadIdx.x;
    cur[threadIdx.x] = rowptr[n <= NN ? n : NN];
    __syncthreads();
    int e1 = bsum[b + 1];
    for (int e = bsum[b] + threadIdx.x; e < e1; e += 256) {
        unsigned p = packed[e];
        int pos = atomicAdd(&cur[p >> 24], 1);
        col[pos] = (int)(p & 0xFFFFFFu);
    }
}

// ---------------- helpers ----------------

__device__ __forceinline__ void fma4(float4& acc, float s, const float4& w) {
    acc.x = fmaf(s, w.x, acc.x);
    acc.y = fmaf(s, w.y, acc.y);
    acc.z = fmaf(s, w.z, acc.z);
    acc.w = fmaf(s, w.w, acc.w);
}

__device__ __forceinline__ float4 scale4(const float4& a, float s) {
    return float4{a.x * s, a.y * s, a.z * s, a.w * s};
}

__device__ __forceinline__ void add4(float4& a, const float4& b) {
    a.x += b.x; a.y += b.y; a.z += b.z; a.w += b.w;
}

__device__ __forceinline__ void xor_reduce4(float4& a, int mask) {
    a.x += __shfl_xor(a.x, mask, 64);
    a.y += __shfl_xor(a.y, mask, 64);
    a.z += __shfl_xor(a.z, mask, 64);
    a.w += __shfl_xor(a.w, mask, 64);
}

__device__ __forceinline__ float4 radd4(const float4& a, const float4& b) {
    return float4{fmaxf(a.x + b.x, 0.f), fmaxf(a.y + b.y, 0.f),
                  fmaxf(a.z + b.z, 0.f), fmaxf(a.w + b.w, 0.f)};
}

// ---------------- prescale: xs = x * dinv ----------------
__global__ __launch_bounds__(256) void k_prescale(const float* __restrict__ x,
                                                  const float* __restrict__ dinv,
                                                  float* __restrict__ xs) {
    int i = blockIdx.x * 256 + threadIdx.x;  // float4 index
    if (i >= NN * 16) return;
    float di = dinv[i >> 4];
    ((float4*)xs)[i] = scale4(((const float4*)x)[i], di);
}

// ---------------- layer-1 gather on prescaled xs ----------------
// agg[d] = dinv_d * ( xs[d] + sum_{s in in(d)} xs[s] )
__global__ __launch_bounds__(256) void k_gather1x(const int* __restrict__ rowptr,
                                                  const int* __restrict__ col,
                                                  const float* __restrict__ xs,
                                                  const float* __restrict__ dinv,
                                                  float* __restrict__ agg) {
    int wave = (blockIdx.x * 256 + threadIdx.x) >> 6;
    int lane = threadIdx.x & 63;
    if (wave >= NN) return;
    int f4 = lane & 15;   // float4 index within 64-float row
    int es = lane >> 4;   // edge sublane 0..3
    int r0 = rowptr[wave], r1 = rowptr[wave + 1];
    const float4* xs4 = (const float4*)xs;
    float4 acc{0, 0, 0, 0};
    if (es == 0) acc = xs4[(size_t)wave * 16 + f4];  // self loop (once)
    int e = r0 + es;
    for (; e + 4 < r1; e += 8) {
        int s0 = col[e];
        int s1 = col[e + 4];
        float4 v0 = xs4[(size_t)s0 * 16 + f4];
        float4 v1 = xs4[(size_t)s1 * 16 + f4];
        add4(acc, v0);
        add4(acc, v1);
    }
    for (; e < r1; e += 4) {
        float4 v = xs4[(size_t)col[e] * 16 + f4];
        add4(acc, v);
    }
    xor_reduce4(acc, 16);
    xor_reduce4(acc, 32);
    if (es == 0)
        ((float4*)agg)[(size_t)wave * 16 + f4] = scale4(acc, dinv[wave]);
}

// ---------------- fused GEMM1 + GEMM2 (wave-local, zero LDS) ----------------
// One wave owns 16 nodes (NN = 6250*16). lane = g*16+f (g=group 0..3, f=0..15).
// Group g owns rows 4g..4g+3 of the wave tile.
// Phase 0: agg tile distributed: lane (g,f) holds row 4g+(f&3), k-chunk
//          [16*(f>>2), +16) as 4 float4s.
// Phase A: h1 = relu(agg@W1 + b1); thread (g,f) computes feats 8f..8f+7 of
//          rows 4g..4g+3 (kept in registers); a-values via __shfl.
// Phase B: y2 = (h1@W2)*dinv; thread (g,f) computes feats 4f..4f+3 of rows
//          4g..4g+3; h-values via __shfl from the owning lane (same wave).
__global__ __launch_bounds__(256) void k_gemm12(const float* __restrict__ agg,
                                                const float* __restrict__ W1,
                                                const float* __restrict__ b1,
                                                const float* __restrict__ W2,
                                                const float* __restrict__ dinv,
                                                float* __restrict__ y2) {
    int tid = threadIdx.x;
    int wv = (blockIdx.x * 256 + tid) >> 6;
    int nb = wv * 16;
    if (nb >= NN) return;
    int lane = tid & 63;
    int g = lane >> 4;
    int f = lane & 15;
    int gbase = g << 4;
    int fx2 = f * 2;

    const float4* agg4 = (const float4*)agg;
    const float4* W14 = (const float4*)W1;  // [64][32] float4
    const float4* W24 = (const float4*)W2;  // [128][16] float4

    // phase 0: distribute agg tile (16 rows x 64 floats) across the wave
    size_t abase = (size_t)(nb + (g << 2) + (f & 3)) * 16 + ((f >> 2) << 2);
    float4 A0 = agg4[abase + 0];
    float4 A1 = agg4[abase + 1];
    float4 A2 = agg4[abase + 2];
    float4 A3 = agg4[abase + 3];

    // phase A accumulators: rows 0..3 x feat-quads (8f..8f+3, 8f+4..8f+7)
    float4 c00{0,0,0,0}, c01{0,0,0,0}, c10{0,0,0,0}, c11{0,0,0,0};
    float4 c20{0,0,0,0}, c21{0,0,0,0}, c30{0,0,0,0}, c31{0,0,0,0};

#define PA_STEP(kk, AJ, COMP)                                                  \
    {                                                                          \
        float vv = AJ.COMP;                                                    \
        float s0 = __shfl(vv, sb + 0, 64);                                     \
        float s1 = __shfl(vv, sb + 1, 64);                                     \
        float s2 = __shfl(vv, sb + 2, 64);                                     \
        float s3 = __shfl(vv, sb + 3, 64);                                     \
        float4 w0 = Wrow[(kk) * 32 + fx2];                                     \
        float4 w1 = Wrow[(kk) * 32 + fx2 + 1];                                 \
        fma4(c00, s0, w0); fma4(c01, s0, w1);                                  \
        fma4(c10, s1, w0); fma4(c11, s1, w1);                                  \
        fma4(c20, s2, w0); fma4(c21, s2, w1);                                  \
        fma4(c30, s3, w0); fma4(c31, s3, w1);                                  \
    }

#pragma unroll
    for (int k0 = 0; k0 < 4; ++k0) {
        int sb = gbase + (k0 << 2);
        const float4* Wrow = W14 + (size_t)(k0 << 4) * 32;
        PA_STEP(0,  A0, x) PA_STEP(1,  A0, y) PA_STEP(2,  A0, z) PA_STEP(3,  A0, w)
        PA_STEP(4,  A1, x) PA_STEP(5,  A1, y) PA_STEP(6,  A1, z) PA_STEP(7,  A1, w)
        PA_STEP(8,  A2, x) PA_STEP(9,  A2, y) PA_STEP(10, A2, z) PA_STEP(11, A2, w)
        PA_STEP(12, A3, x) PA_STEP(13, A3, y) PA_STEP(14, A3, z) PA_STEP(15, A3, w)
    }
#undef PA_STEP

    // epilogue A: h1 in registers (rows 0..3, feats 8f..8f+7)
    float4 bb0 = ((const float4*)b1)[fx2];
    float4 bb1 = ((const float4*)b1)[fx2 + 1];
    float4 h0a = radd4(c00, bb0), h0b = radd4(c01, bb1);
    float4 h1a = radd4(c10, bb0), h1b = radd4(c11, bb1);
    float4 h2a = radd4(c20, bb0), h2b = radd4(c21, bb1);
    float4 h3a = radd4(c30, bb0), h3b = radd4(c31, bb1);

    // phase B accumulators: rows 0..3 x feat-quad 4f..4f+3
    float4 d0{0,0,0,0}, d1{0,0,0,0}, d2{0,0,0,0}, d3{0,0,0,0};

#define PB_STEP(kk, H0, H1, H2, H3, COMP)                                      \
    {                                                                          \
        float s0 = __shfl(H0.COMP, srcB, 64);                                  \
        float s1 = __shfl(H1.COMP, srcB, 64);                                  \
        float s2 = __shfl(H2.COMP, srcB, 64);                                  \
        float s3 = __shfl(H3.COMP, srcB, 64);                                  \
        float4 w = W2row[(kk) * 16 + f];                                       \
        fma4(d0, s0, w); fma4(d1, s1, w); fma4(d2, s2, w); fma4(d3, s3, w);    \
    }

#pragma unroll 4
    for (int k0 = 0; k0 < 16; ++k0) {
        int srcB = gbase + k0;
        const float4* W2row = W24 + (size_t)(k0 << 3) * 16;
        PB_STEP(0, h0a, h1a, h2a, h3a, x)
        PB_STEP(1, h0a, h1a, h2a, h3a, y)
        PB_STEP(2, h0a, h1a, h2a, h3a, z)
        PB_STEP(3, h0a, h1a, h2a, h3a, w)
        PB_STEP(4, h0b, h1b, h2b, h3b, x)
        PB_STEP(5, h0b, h1b, h2b, h3b, y)
        PB_STEP(6, h0b, h1b, h2b, h3b, z)
        PB_STEP(7, h0b, h1b, h2b, h3b, w)
    }
#undef PB_STEP

    // epilogue B
    int n0 = nb + (g << 2);
    float4* y24 = (float4*)y2;  // [N][16] float4
    y24[(size_t)(n0 + 0) * 16 + f] = scale4(d0, dinv[n0 + 0]);
    y24[(size_t)(n0 + 1) * 16 + f] = scale4(d1, dinv[n0 + 1]);
    y24[(size_t)(n0 + 2) * 16 + f] = scale4(d2, dinv[n0 + 2]);
    y24[(size_t)(n0 + 3) * 16 + f] = scale4(d3, dinv[n0 + 3]);
}

// ---------------- layer-2 gather fused with FC head ----------------
// acc = y2[d] + sum y2[s]; out[d] = relu(acc*dinv_d + b2) . Wfc + bfc
__global__ __launch_bounds__(256) void k_gather2_final(const int* __restrict__ rowptr,
                                                       const int* __restrict__ col,
                                                       const float* __restrict__ y2,
                                                       const float* __restrict__ dinv,
                                                       const float* __restrict__ b2,
                                                       const float* __restrict__ Wfc,
                                                       const float* __restrict__ bfc,
                                                       float* __restrict__ out) {
    int wave = (blockIdx.x * 256 + threadIdx.x) >> 6;
    int lane = threadIdx.x & 63;
    if (wave >= NN) return;
    int f4 = lane & 15;
    int es = lane >> 4;
    int r0 = rowptr[wave], r1 = rowptr[wave + 1];
    const float4* y24 = (const float4*)y2;
    float4 acc{0, 0, 0, 0};
    if (es == 0) acc = y24[(size_t)wave * 16 + f4];  // self loop (once)
    int e = r0 + es;
    for (; e + 4 < r1; e += 8) {
        int s0 = col[e];
        int s1 = col[e + 4];
        float4 v0 = y24[(size_t)s0 * 16 + f4];
        float4 v1 = y24[(size_t)s1 * 16 + f4];
        add4(acc, v0);
        add4(acc, v1);
    }
    for (; e < r1; e += 4) {
        float4 v = y24[(size_t)col[e] * 16 + f4];
        add4(acc, v);
    }
    xor_reduce4(acc, 16);
    xor_reduce4(acc, 32);
    // every lane now holds the feature-group sum for its f4 (4 copies)
    float di = dinv[wave];
    float4 b = ((const float4*)b2)[f4];
    float4 w = ((const float4*)Wfc)[f4];
    float p = fmaxf(fmaf(acc.x, di, b.x), 0.f) * w.x
            + fmaxf(fmaf(acc.y, di, b.y), 0.f) * w.y
            + fmaxf(fmaf(acc.z, di, b.z), 0.f) * w.z
            + fmaxf(fmaf(acc.w, di, b.w), 0.f) * w.w;
    // sum the 16 f4 groups (each 16-lane block holds all 16 f4 values)
    p += __shfl_xor(p, 1, 64);
    p += __shfl_xor(p, 2, 64);
    p += __shfl_xor(p, 4, 64);
    p += __shfl_xor(p, 8, 64);
    if (lane == 0) out[wave] = p + bfc[0];
}

extern "C" void kernel_launch(void* const* d_in, const int* in_sizes, int n_in,
                              void* d_out, int out_size, void* d_ws, size_t ws_size,
                              hipStream_t stream) {
    const float* x   = (const float*)d_in[0];
    const int*   ei  = (const int*)d_in[1];   // [2, E] int
    const float* W1  = (const float*)d_in[2];
    const float* b1  = (const float*)d_in[3];
    const float* W2  = (const float*)d_in[4];
    const float* b2  = (const float*)d_in[5];
    const float* Wfc = (const float*)d_in[6];
    const float* bfc = (const float*)d_in[7];
    float* out = (float*)d_out;

    const int* src = ei;
    const int* dst = ei + NE;

    char* ws = (char*)d_ws;
    size_t o = 0;
    auto alloc = [&](size_t bytes) { char* p = ws + o; o += (bytes + 255) & ~size_t(255); return p; };
    int*   cnt    = (int*)alloc(NN * 4);
    int*   rowptr = (int*)alloc((NN + 1) * 4);
    int*   bsum   = (int*)alloc(512 * 4);
    int*   gcur   = (int*)alloc(NB * 4);
    float* dinv   = (float*)alloc(NN * 4);
    int*   col    = (int*)alloc((size_t)NE * 4);
    float* xs     = (float*)alloc((size_t)NN * D0 * 4);  // 25.6 MB
    float* agg1x  = (float*)alloc((size_t)NN * D0 * 4);  // 25.6 MB
    float* y2     = (float*)alloc((size_t)NN * D2 * 4);  // 25.6 MB
    unsigned* packed = (unsigned*)agg1x;  // dead before k_gather1x writes agg

    const int NBn = (NN + 255) / 256;
    const int NBe = (NE + 255) / 256;

    k_zero_cnt   <<<NBn, 256, 0, stream>>>(cnt);
    k_hist       <<<NBe, 256, 0, stream>>>(dst, cnt);
    k_scan_block <<<NBn, 256, 0, stream>>>(cnt, rowptr, bsum);
    k_scan_bsum  <<<1, 512, 0, stream>>>(bsum, gcur);
    k_scan_add   <<<NBn, 256, 0, stream>>>(rowptr, bsum);
    k_dinv       <<<NBn, 256, 0, stream>>>(cnt, dinv);
    k_part       <<<(NE + TILE - 1) / TILE, 256, 0, stream>>>(src, dst, gcur, packed);
    k_fill2      <<<NB, 256, 0, stream>>>(bsum, rowptr, packed, col);
    k_prescale   <<<(NN * 16 + 255) / 256, 256, 0, stream>>>(x, dinv, xs);

    k_gather1x   <<<(NN * 64 + 255) / 256, 256, 0, stream>>>(rowptr, col, xs, dinv, agg1x);
    k_gemm12     <<<(NN / 16 + 3) / 4, 256, 0, stream>>>(agg1x, W1, b1, W2, dinv, y2);
    k_gather2_final<<<(NN * 64 + 255) / 256, 256, 0, stream>>>(rowptr, col, y2, dinv,
                                                               b2, Wfc, bfc, out);
}

// Round 8
// 383.278 us; speedup vs baseline: 1.0338x; 1.0338x over previous
//
#include <hip/hip_runtime.h>

// ProteinGCN: 2x GCNConv(+relu) + FC head. N=100k, E=1.6M, 64->128->64->1.
// Round 7: hybrid gemm12. Round-6's all-register/shfl version regressed
// (VGPR squeezed to 52 -> serialization; phase B had 1 shfl : 4 FMA).
// Hybrid: phase A = round-6 shfl broadcast (1:8 shfl:FMA, A-tile straight
// from global into distributed registers, no `as` LDS tile); h1 -> per-wave
// LDS region (16x132 floats/wave, 33.8 KB/block vs round-5's 51.2 KB);
// phase B = round-5 ds_read_b128 (4-address broadcast, conflict-light).
// LDS drop doubles blocks/CU (2->4); h in LDS relieves register pressure.

constexpr int NN = 100000;
constexpr int NE = 1600000;
constexpr int D0 = 64;   // input dim
constexpr int D1 = 128;  // hidden 1
constexpr int D2 = 64;   // hidden 2
constexpr int NB = (NN + 255) / 256;  // 391 buckets
constexpr int TILE = 8192;            // edges per k_part block
constexpr int HSTR = 132;             // h1 LDS row stride (floats)
constexpr int HSW = 16 * HSTR;        // h1 floats per wave region

// ---------------- CSR build ----------------

__global__ __launch_bounds__(256) void k_zero_cnt(int* __restrict__ cnt) {
    int i = blockIdx.x * 256 + threadIdx.x;
    if (i < NN) cnt[i] = 0;
}

__global__ __launch_bounds__(256) void k_hist(const int* __restrict__ dst,
                                              int* __restrict__ cnt) {
    int e = blockIdx.x * 256 + threadIdx.x;
    if (e < NE) atomicAdd(&cnt[dst[e]], 1);
}

__global__ __launch_bounds__(256) void k_scan_block(const int* __restrict__ cnt,
                                                    int* __restrict__ rowptr,
                                                    int* __restrict__ bsum) {
    __shared__ int s[256];
    int tid = threadIdx.x;
    int i = blockIdx.x * 256 + tid;
    int v = (i < NN) ? cnt[i] : 0;
    s[tid] = v;
    __syncthreads();
#pragma unroll
    for (int off = 1; off < 256; off <<= 1) {
        int t = (tid >= off) ? s[tid - off] : 0;
        __syncthreads();
        s[tid] += t;
        __syncthreads();
    }
    if (i < NN) rowptr[i] = s[tid] - v;  // exclusive
    if (tid == 255) bsum[blockIdx.x] = s[255];
}

__global__ __launch_bounds__(512) void k_scan_bsum(int* __restrict__ bsum,
                                                   int* __restrict__ gcur) {
    __shared__ int s[512];
    int tid = threadIdx.x;
    int v = (tid < NB) ? bsum[tid] : 0;
    s[tid] = v;
    __syncthreads();
#pragma unroll
    for (int off = 1; off < 512; off <<= 1) {
        int t = (tid >= off) ? s[tid - off] : 0;
        __syncthreads();
        s[tid] += t;
        __syncthreads();
    }
    int ex = s[tid] - v;  // exclusive scan
    if (tid <= NB) bsum[tid] = ex;   // bsum[NB] == NE
    if (tid < NB) gcur[tid] = ex;
}

__global__ __launch_bounds__(256) void k_scan_add(int* __restrict__ rowptr,
                                                  const int* __restrict__ bsum) {
    int i = blockIdx.x * 256 + threadIdx.x;
    if (i < NN) rowptr[i] += bsum[i >> 8];
    if (i == 0) rowptr[NN] = NE;
}

__global__ __launch_bounds__(256) void k_dinv(const int* __restrict__ cnt,
                                              float* __restrict__ dinv) {
    int i = blockIdx.x * 256 + threadIdx.x;
    if (i < NN) dinv[i] = rsqrtf((float)(cnt[i] + 1));
}

// ---- phase 1: partition edges into dst-buckets, packed (dl<<24)|src ----
__global__ __launch_bounds__(256) void k_part(const int* __restrict__ src,
                                              const int* __restrict__ dst,
                                              int* __restrict__ gcur,
                                              unsigned* __restrict__ packed) {
    __shared__ int cnt_s[NB];
    __shared__ int gbase_s[NB];
    __shared__ int cur_s[NB];
    int tid = threadIdx.x;
    int e0 = blockIdx.x * TILE;
    int ecnt = NE - e0 < TILE ? NE - e0 : TILE;
    for (int i = tid; i < NB; i += 256) cnt_s[i] = 0;
    __syncthreads();
    for (int i = tid; i < ecnt; i += 256)
        atomicAdd(&cnt_s[dst[e0 + i] >> 8], 1);
    __syncthreads();
    for (int i = tid; i < NB; i += 256) {
        int c = cnt_s[i];
        gbase_s[i] = c ? atomicAdd(&gcur[i], c) : 0;
        cur_s[i] = 0;
    }
    __syncthreads();
    for (int i = tid; i < ecnt; i += 256) {
        int d = dst[e0 + i];
        int s = src[e0 + i];
        int b = d >> 8;
        int slot = atomicAdd(&cur_s[b], 1);
        packed[gbase_s[b] + slot] = ((unsigned)(d & 255) << 24) | (unsigned)s;
    }
}

// ---- phase 2: one block per bucket, LDS node cursors, local col writes ----
__global__ __launch_bounds__(256) void k_fill2(const int* __restrict__ bsum,
                                               const int* __restrict__ rowptr,
                                               const unsigned* __restrict__ packed,
                                               int* __restrict__ col) {
    __shared__ int cur[256];
    int b = blockIdx.x;
    int n = (b << 8) + threadIdx.x;
    cur[threadIdx.x] = rowptr[n <= NN ? n : NN];
    __syncthreads();
    int e1 = bsum[b + 1];
    for (int e = bsum[b] + threadIdx.x; e < e1; e += 256) {
        unsigned p = packed[e];
        int pos = atomicAdd(&cur[p >> 24], 1);
        col[pos] = (int)(p & 0xFFFFFFu);
    }
}

// ---------------- helpers ----------------

__device__ __forceinline__ void fma4(float4& acc, float s, const float4& w) {
    acc.x = fmaf(s, w.x, acc.x);
    acc.y = fmaf(s, w.y, acc.y);
    acc.z = fmaf(s, w.z, acc.z);
    acc.w = fmaf(s, w.w, acc.w);
}

__device__ __forceinline__ float4 scale4(const float4& a, float s) {
    return float4{a.x * s, a.y * s, a.z * s, a.w * s};
}

__device__ __forceinline__ void add4(float4& a, const float4& b) {
    a.x += b.x; a.y += b.y; a.z += b.z; a.w += b.w;
}

__device__ __forceinline__ void xor_reduce4(float4& a, int mask) {
    a.x += __shfl_xor(a.x, mask, 64);
    a.y += __shfl_xor(a.y, mask, 64);
    a.z += __shfl_xor(a.z, mask, 64);
    a.w += __shfl_xor(a.w, mask, 64);
}

__device__ __forceinline__ float4 radd4(const float4& a, const float4& b) {
    return float4{fmaxf(a.x + b.x, 0.f), fmaxf(a.y + b.y, 0.f),
                  fmaxf(a.z + b.z, 0.f), fmaxf(a.w + b.w, 0.f)};
}

// ---------------- prescale: xs = x * dinv ----------------
__global__ __launch_bounds__(256) void k_prescale(const float* __restrict__ x,
                                                  const float* __restrict__ dinv,
                                                  float* __restrict__ xs) {
    int i = blockIdx.x * 256 + threadIdx.x;  // float4 index
    if (i >= NN * 16) return;
    float di = dinv[i >> 4];
    ((float4*)xs)[i] = scale4(((const float4*)x)[i], di);
}

// ---------------- layer-1 gather on prescaled xs ----------------
// agg[d] = dinv_d * ( xs[d] + sum_{s in in(d)} xs[s] )
__global__ __launch_bounds__(256) void k_gather1x(const int* __restrict__ rowptr,
                                                  const int* __restrict__ col,
                                                  const float* __restrict__ xs,
                                                  const float* __restrict__ dinv,
                                                  float* __restrict__ agg) {
    int wave = (blockIdx.x * 256 + threadIdx.x) >> 6;
    int lane = threadIdx.x & 63;
    if (wave >= NN) return;
    int f4 = lane & 15;   // float4 index within 64-float row
    int es = lane >> 4;   // edge sublane 0..3
    int r0 = rowptr[wave], r1 = rowptr[wave + 1];
    const float4* xs4 = (const float4*)xs;
    float4 acc{0, 0, 0, 0};
    if (es == 0) acc = xs4[(size_t)wave * 16 + f4];  // self loop (once)
    int e = r0 + es;
    for (; e + 4 < r1; e += 8) {
        int s0 = col[e];
        int s1 = col[e + 4];
        float4 v0 = xs4[(size_t)s0 * 16 + f4];
        float4 v1 = xs4[(size_t)s1 * 16 + f4];
        add4(acc, v0);
        add4(acc, v1);
    }
    for (; e < r1; e += 4) {
        float4 v = xs4[(size_t)col[e] * 16 + f4];
        add4(acc, v);
    }
    xor_reduce4(acc, 16);
    xor_reduce4(acc, 32);
    if (es == 0)
        ((float4*)agg)[(size_t)wave * 16 + f4] = scale4(acc, dinv[wave]);
}

// ---------------- fused GEMM1 + GEMM2 (hybrid) ----------------
// One wave owns 16 nodes. lane = g*16+f (g 0..3, f 0..15); group g owns rows
// 4g..4g+3. Phase 0: agg tile distributed: lane (g,f) holds row 4g+(f&3),
// k-chunk [16*(f>>2),+16). Phase A: h1 = relu(agg@W1+b1); thread (g,f)
// computes feats 8f..8f+7 of rows 4g..4g+3 (a-values via shfl broadcast),
// then stores h to this wave's private LDS region. Phase B: y2=(h1@W2)*dinv;
// thread (g,f) computes feats 4f..4f+3 of rows 4g..4g+3 via ds_read_b128
// (4 unique addrs -> 16-lane broadcast each).
__global__ __launch_bounds__(256) void k_gemm12(const float* __restrict__ agg,
                                                const float* __restrict__ W1,
                                                const float* __restrict__ b1,
                                                const float* __restrict__ W2,
                                                const float* __restrict__ dinv,
                                                float* __restrict__ y2) {
    __shared__ float hs[4 * HSW];  // 33.8 KB
    int tid = threadIdx.x;
    int w = tid >> 6;
    int lane = tid & 63;
    int wv = blockIdx.x * 4 + w;
    int nb = wv * 16;
    bool active = nb < NN;
    int g = lane >> 4;
    int f = lane & 15;
    int gbase = g << 4;
    int fx2 = f * 2;
    float* hw = hs + w * HSW;

    if (active) {
        const float4* agg4 = (const float4*)agg;
        const float4* W14 = (const float4*)W1;  // [64][32] float4

        // phase 0: distribute agg tile (16 rows x 64 floats) across the wave
        size_t abase = (size_t)(nb + (g << 2) + (f & 3)) * 16 + ((f >> 2) << 2);
        float4 A0 = agg4[abase + 0];
        float4 A1 = agg4[abase + 1];
        float4 A2 = agg4[abase + 2];
        float4 A3 = agg4[abase + 3];

        float4 c00{0,0,0,0}, c01{0,0,0,0}, c10{0,0,0,0}, c11{0,0,0,0};
        float4 c20{0,0,0,0}, c21{0,0,0,0}, c30{0,0,0,0}, c31{0,0,0,0};

#define PA_STEP(kk, AJ, COMP)                                                  \
    {                                                                          \
        float vv = AJ.COMP;                                                    \
        float s0 = __shfl(vv, sb + 0, 64);                                     \
        float s1 = __shfl(vv, sb + 1, 64);                                     \
        float s2 = __shfl(vv, sb + 2, 64);                                     \
        float s3 = __shfl(vv, sb + 3, 64);                                     \
        float4 w0 = Wrow[(kk) * 32 + fx2];                                     \
        float4 w1 = Wrow[(kk) * 32 + fx2 + 1];                                 \
        fma4(c00, s0, w0); fma4(c01, s0, w1);                                  \
        fma4(c10, s1, w0); fma4(c11, s1, w1);                                  \
        fma4(c20, s2, w0); fma4(c21, s2, w1);                                  \
        fma4(c30, s3, w0); fma4(c31, s3, w1);                                  \
    }

#pragma unroll
        for (int k0 = 0; k0 < 4; ++k0) {
            int sb = gbase + (k0 << 2);
            const float4* Wrow = W14 + (size_t)(k0 << 4) * 32;
            PA_STEP(0,  A0, x) PA_STEP(1,  A0, y) PA_STEP(2,  A0, z) PA_STEP(3,  A0, w)
            PA_STEP(4,  A1, x) PA_STEP(5,  A1, y) PA_STEP(6,  A1, z) PA_STEP(7,  A1, w)
            PA_STEP(8,  A2, x) PA_STEP(9,  A2, y) PA_STEP(10, A2, z) PA_STEP(11, A2, w)
            PA_STEP(12, A3, x) PA_STEP(13, A3, y) PA_STEP(14, A3, z) PA_STEP(15, A3, w)
        }
#undef PA_STEP

        // epilogue A: relu(+bias), store h rows 4g..4g+3 feats 8f..8f+7 to LDS
        float4 bb0 = ((const float4*)b1)[fx2];
        float4 bb1 = ((const float4*)b1)[fx2 + 1];
        float* h0 = hw + (g << 2) * HSTR + (f << 3);
        *(float4*)(h0)             = radd4(c00, bb0);
        *(float4*)(h0 + 4)         = radd4(c01, bb1);
        *(float4*)(h0 + HSTR)      = radd4(c10, bb0);
        *(float4*)(h0 + HSTR + 4)  = radd4(c11, bb1);
        *(float4*)(h0 + 2*HSTR)    = radd4(c20, bb0);
        *(float4*)(h0 + 2*HSTR+4)  = radd4(c21, bb1);
        *(float4*)(h0 + 3*HSTR)    = radd4(c30, bb0);
        *(float4*)(h0 + 3*HSTR+4)  = radd4(c31, bb1);
    }
    __syncthreads();
    if (active) {
        const float4* W24 = (const float4*)W2;  // [128][16] float4
        const float* hr = hw + (g << 2) * HSTR;
        float4 d0{0,0,0,0}, d1{0,0,0,0}, d2{0,0,0,0}, d3{0,0,0,0};
#pragma unroll 4
        for (int k = 0; k < D1; k += 4) {
            float4 a0 = *(const float4*)(hr + k);
            float4 a1 = *(const float4*)(hr + HSTR + k);
            float4 a2 = *(const float4*)(hr + 2 * HSTR + k);
            float4 a3 = *(const float4*)(hr + 3 * HSTR + k);
            float4 w0 = W24[(k + 0) * 16 + f];
            float4 w1 = W24[(k + 1) * 16 + f];
            float4 w2 = W24[(k + 2) * 16 + f];
            float4 w3 = W24[(k + 3) * 16 + f];
            fma4(d0, a0.x, w0); fma4(d0, a0.y, w1); fma4(d0, a0.z, w2); fma4(d0, a0.w, w3);
            fma4(d1, a1.x, w0); fma4(d1, a1.y, w1); fma4(d1, a1.z, w2); fma4(d1, a1.w, w3);
            fma4(d2, a2.x, w0); fma4(d2, a2.y, w1); fma4(d2, a2.z, w2); fma4(d2, a2.w, w3);
            fma4(d3, a3.x, w0); fma4(d3, a3.y, w1); fma4(d3, a3.z, w2); fma4(d3, a3.w, w3);
        }
        int n0 = nb + (g << 2);
        float4* y24 = (float4*)y2;  // [N][16] float4
        y24[(size_t)(n0 + 0) * 16 + f] = scale4(d0, dinv[n0 + 0]);
        y24[(size_t)(n0 + 1) * 16 + f] = scale4(d1, dinv[n0 + 1]);
        y24[(size_t)(n0 + 2) * 16 + f] = scale4(d2, dinv[n0 + 2]);
        y24[(size_t)(n0 + 3) * 16 + f] = scale4(d3, dinv[n0 + 3]);
    }
}

// ---------------- layer-2 gather fused with FC head ----------------
// acc = y2[d] + sum y2[s]; out[d] = relu(acc*dinv_d + b2) . Wfc + bfc
__global__ __launch_bounds__(256) void k_gather2_final(const int* __restrict__ rowptr,
                                                       const int* __restrict__ col,
                                                       const float* __restrict__ y2,
                                                       const float* __restrict__ dinv,
                                                       const float* __restrict__ b2,
                                                       const float* __restrict__ Wfc,
                                                       const float* __restrict__ bfc,
                                                       float* __restrict__ out) {
    int wave = (blockIdx.x * 256 + threadIdx.x) >> 6;
    int lane = threadIdx.x & 63;
    if (wave >= NN) return;
    int f4 = lane & 15;
    int es = lane >> 4;
    int r0 = rowptr[wave], r1 = rowptr[wave + 1];
    const float4* y24 = (const float4*)y2;
    float4 acc{0, 0, 0, 0};
    if (es == 0) acc = y24[(size_t)wave * 16 + f4];  // self loop (once)
    int e = r0 + es;
    for (; e + 4 < r1; e += 8) {
        int s0 = col[e];
        int s1 = col[e + 4];
        float4 v0 = y24[(size_t)s0 * 16 + f4];
        float4 v1 = y24[(size_t)s1 * 16 + f4];
        add4(acc, v0);
        add4(acc, v1);
    }
    for (; e < r1; e += 4) {
        float4 v = y24[(size_t)col[e] * 16 + f4];
        add4(acc, v);
    }
    xor_reduce4(acc, 16);
    xor_reduce4(acc, 32);
    float di = dinv[wave];
    float4 b = ((const float4*)b2)[f4];
    float4 w = ((const float4*)Wfc)[f4];
    float p = fmaxf(fmaf(acc.x, di, b.x), 0.f) * w.x
            + fmaxf(fmaf(acc.y, di, b.y), 0.f) * w.y
            + fmaxf(fmaf(acc.z, di, b.z), 0.f) * w.z
            + fmaxf(fmaf(acc.w, di, b.w), 0.f) * w.w;
    p += __shfl_xor(p, 1, 64);
    p += __shfl_xor(p, 2, 64);
    p += __shfl_xor(p, 4, 64);
    p += __shfl_xor(p, 8, 64);
    if (lane == 0) out[wave] = p + bfc[0];
}

extern "C" void kernel_launch(void* const* d_in, const int* in_sizes, int n_in,
                              void* d_out, int out_size, void* d_ws, size_t ws_size,
                              hipStream_t stream) {
    const float* x   = (const float*)d_in[0];
    const int*   ei  = (const int*)d_in[1];   // [2, E] int
    const float* W1  = (const float*)d_in[2];
    const float* b1  = (const float*)d_in[3];
    const float* W2  = (const float*)d_in[4];
    const float* b2  = (const float*)d_in[5];
    const float* Wfc = (const float*)d_in[6];
    const float* bfc = (const float*)d_in[7];
    float* out = (float*)d_out;

    const int* src = ei;
    const int* dst = ei + NE;

    char* ws = (char*)d_ws;
    size_t o = 0;
    auto alloc = [&](size_t bytes) { char* p = ws + o; o += (bytes + 255) & ~size_t(255); return p; };
    int*   cnt    = (int*)alloc(NN * 4);
    int*   rowptr = (int*)alloc((NN + 1) * 4);
    int*   bsum   = (int*)alloc(512 * 4);
    int*   gcur   = (int*)alloc(NB * 4);
    float* dinv   = (float*)alloc(NN * 4);
    int*   col    = (int*)alloc((size_t)NE * 4);
    float* xs     = (float*)alloc((size_t)NN * D0 * 4);  // 25.6 MB
    float* agg1x  = (float*)alloc((size_t)NN * D0 * 4);  // 25.6 MB
    float* y2     = (float*)alloc((size_t)NN * D2 * 4);  // 25.6 MB
    unsigned* packed = (unsigned*)agg1x;  // dead before k_gather1x writes agg

    const int NBn = (NN + 255) / 256;
    const int NBe = (NE + 255) / 256;

    k_zero_cnt   <<<NBn, 256, 0, stream>>>(cnt);
    k_hist       <<<NBe, 256, 0, stream>>>(dst, cnt);
    k_scan_block <<<NBn, 256, 0, stream>>>(cnt, rowptr, bsum);
    k_scan_bsum  <<<1, 512, 0, stream>>>(bsum, gcur);
    k_scan_add   <<<NBn, 256, 0, stream>>>(rowptr, bsum);
    k_dinv       <<<NBn, 256, 0, stream>>>(cnt, dinv);
    k_part       <<<(NE + TILE - 1) / TILE, 256, 0, stream>>>(src, dst, gcur, packed);
    k_fill2      <<<NB, 256, 0, stream>>>(bsum, rowptr, packed, col);
    k_prescale   <<<(NN * 16 + 255) / 256, 256, 0, stream>>>(x, dinv, xs);

    k_gather1x   <<<(NN * 64 + 255) / 256, 256, 0, stream>>>(rowptr, col, xs, dinv, agg1x);
    k_gemm12     <<<(NN / 16 + 3) / 4, 256, 0, stream>>>(agg1x, W1, b1, W2, dinv, y2);
    k_gather2_final<<<(NN * 64 + 255) / 256, 256, 0, stream>>>(rowptr, col, y2, dinv,
                                                               b2, Wfc, bfc, out);
}